// Round 4
// baseline (1100.994 us; speedup 1.0000x reference)
//
#include <hip/hip_runtime.h>
#include <cstdint>

#define B_ 4
#define T_ 2048
#define D_ 1024
#define E_ 8
#define F_ 4096
#define K_ 2
#define N_ (B_*T_)      // 8192 tokens
#define NR_ (N_*K_)     // 16384 routed slots

#define TM 128
#define BK 64
#define MAXP (NR_ + E_*TM)       // padded slot capacity (17408)
#define MAXMB (NR_/TM + E_)      // max M-blocks (136) == 8 XCDs * 17
#define MBPX (MAXMB/8)           // 17 M-blocks per XCD chunk
#define BUFS (128*BK)            // 8192 ushorts = 16 KB per matrix per buffer

typedef __attribute__((ext_vector_type(8))) short short8;
typedef __attribute__((ext_vector_type(4))) float f32x4;

typedef const __attribute__((address_space(1))) unsigned int* gp1_t;
typedef __attribute__((address_space(3))) unsigned int* lp3_t;

__device__ __forceinline__ void gl_lds16(const void* g, void* l) {
    __builtin_amdgcn_global_load_lds((gp1_t)g, (lp3_t)l, 16, 0, 0);
}

__device__ __forceinline__ unsigned short f2b(float f) {
    union { float f; unsigned int u; } v; v.f = f;
    unsigned int u = v.u;
    return (unsigned short)((u + 0x7FFFu + ((u >> 16) & 1u)) >> 16);
}

__device__ __forceinline__ float b2f(unsigned short u) {
    union { unsigned int i; float f; } v; v.i = ((unsigned int)u) << 16;
    return v.f;
}

__device__ __forceinline__ float gelu_exact(float x) {
    return 0.5f * x * (1.0f + erff(x * 0.70710678118654752440f));
}

// ---------------- gate: fp32 logits, top-2, softmax; fused x->bf16 cast ----
__global__ __launch_bounds__(256) void gate_kernel(
    const float* __restrict__ x, const float* __restrict__ Wg,
    const float* __restrict__ bg, int* __restrict__ topi,
    float* __restrict__ topw, int* __restrict__ counts,
    unsigned short* __restrict__ Xb) {
    int tid  = threadIdx.x;
    int lane = tid & 63;
    int tok  = blockIdx.x * 4 + (tid >> 6);
    int e = lane & 7;
    int c = lane >> 3;
    const float4* xp = (const float4*)(x + (size_t)tok * D_ + c * 128);
    const float*  wp = Wg + (size_t)(c * 128) * E_ + e;
    float acc = 0.f;
    #pragma unroll 8
    for (int i = 0; i < 32; ++i) {
        float4 xv = xp[i];
        acc += xv.x * wp[(i*4+0)*E_];
        acc += xv.y * wp[(i*4+1)*E_];
        acc += xv.z * wp[(i*4+2)*E_];
        acc += xv.w * wp[(i*4+3)*E_];
    }
    // fused bf16 cast: lane owns floats [lane*16, lane*16+16) (L1-hot re-read)
    {
        const float4* xw = (const float4*)(x + (size_t)tok * D_ + lane * 16);
        #pragma unroll
        for (int j = 0; j < 4; ++j) {
            float4 v = xw[j];
            ushort4 o; o.x = f2b(v.x); o.y = f2b(v.y); o.z = f2b(v.z); o.w = f2b(v.w);
            *(ushort4*)&Xb[(size_t)tok * D_ + lane*16 + j*4] = o;
        }
    }
    acc += __shfl_xor(acc, 8, 64);
    acc += __shfl_xor(acc, 16, 64);
    acc += __shfl_xor(acc, 32, 64);
    float logit = acc + bg[e];
    float v1 = -3.4e38f, v2 = -3.4e38f; int i1 = -1, i2 = -1;
    for (int ee = 0; ee < 8; ++ee) {
        float le = __shfl(logit, ee, 64);
        if (le > v1) { v2 = v1; i2 = i1; v1 = le; i1 = ee; }
        else if (le > v2) { v2 = le; i2 = ee; }
    }
    if (lane == 0) {
        float p2 = expf(v2 - v1);
        float s  = 1.0f + p2;
        topi[tok*2]   = i1; topw[tok*2]   = 1.0f / s;
        topi[tok*2+1] = i2; topw[tok*2+1] = p2 / s;
        atomicAdd(&counts[i1], 1);    // fire-and-forget (no return use)
        atomicAdd(&counts[i2], 1);
    }
}

// scan: padded offsets + flat M-block tables
__global__ void scan_kernel(const int* __restrict__ counts,
                            int* __restrict__ offs, int* __restrict__ cursors,
                            int* __restrict__ mb_e, int* __restrict__ mb_m0) {
    if (threadIdx.x == 0) {
        int s = 0, mb = 0;
        for (int e = 0; e < E_; ++e) {
            offs[e] = s; cursors[e] = s;
            int nb = (counts[e] + TM - 1) / TM;
            for (int i = 0; i < nb; ++i) { mb_e[mb] = e; mb_m0[mb] = s + i*TM; ++mb; }
            s += nb * TM;
        }
        offs[E_] = s;
        for (int b = mb; b < MAXMB; ++b) mb_e[b] = -1;
    }
}

// wave-aggregated scatter: ~16 atomics/wave instead of 128 contended ones
__global__ __launch_bounds__(256) void scatter_kernel(
    const int* __restrict__ topi, int* __restrict__ cursors,
    int* __restrict__ perm, int* __restrict__ slots) {
    int t = blockIdx.x * blockDim.x + threadIdx.x;
    int lane = threadIdx.x & 63;
    unsigned long long lanebit_m1 = (1ULL << lane) - 1ULL;
    #pragma unroll
    for (int k = 0; k < K_; ++k) {
        int e = (t < N_) ? topi[t*2 + k] : -1;
        int pos = 0;
        #pragma unroll
        for (int ee = 0; ee < E_; ++ee) {
            unsigned long long mask = __ballot(e == ee);
            if (mask) {
                int leader = __ffsll((long long)mask) - 1;
                int base = 0;
                if (lane == leader)
                    base = atomicAdd(&cursors[ee], __popcll(mask));
                base = __shfl(base, leader, 64);
                if (e == ee)
                    pos = base + __popcll(mask & lanebit_m1);
            }
        }
        if (t < N_) {
            perm[pos] = t;
            slots[t*2 + k] = pos;
        }
    }
}

// batched fp32 [R,C] -> bf16 [C,R]; 64x64 tile, vectorized
__global__ __launch_bounds__(256) void tcast_kernel(
    const float* __restrict__ src, unsigned short* __restrict__ dst, int R, int C) {
    __shared__ float tile[64][65];
    int rb = blockIdx.x * 64, cb = blockIdx.y * 64;
    const float* s = src + (size_t)blockIdx.z * R * C;
    unsigned short* d = dst + (size_t)blockIdx.z * R * C;
    int tx = threadIdx.x & 15, ty = threadIdx.x >> 4;   // 16 x 16
    #pragma unroll
    for (int i = 0; i < 4; ++i) {
        int r = ty + i*16;
        float4 v = *(const float4*)&s[(size_t)(rb + r) * C + cb + tx*4];
        tile[r][tx*4+0] = v.x; tile[r][tx*4+1] = v.y;
        tile[r][tx*4+2] = v.z; tile[r][tx*4+3] = v.w;
    }
    __syncthreads();
    #pragma unroll
    for (int i = 0; i < 4; ++i) {
        int c = ty + i*16;                               // dst row
        ushort4 o;
        o.x = f2b(tile[tx*4+0][c]);
        o.y = f2b(tile[tx*4+1][c]);
        o.z = f2b(tile[tx*4+2][c]);
        o.w = f2b(tile[tx*4+3][c]);
        *(ushort4*)&d[(size_t)(cb + c) * R + rb + tx*4] = o;
    }
}

// ---------------- GEMM1: H = gelu(Xb[perm] @ W1[e] + b1[e]) ----------------
// 128x128 tile, BK=64, XCD chunk swizzle (r2: FETCH 548->283 MB, verified).
// r3: T4 counted-vmcnt + LDS dbuf. Raw s_barrier (NOT __syncthreads: that
// re-emits vmcnt(0) drain). Prefetch tile k+1 (8 gl_lds), then vmcnt(8):
// tile k's loads retired, k+1's stay in flight across the barrier.
__global__ __launch_bounds__(256, 2) void ffn1_kernel(
    const unsigned short* __restrict__ Xb, const unsigned short* __restrict__ W1t,
    const float* __restrict__ b1, const int* __restrict__ perm,
    const int* __restrict__ mb_e, const int* __restrict__ mb_m0,
    unsigned short* __restrict__ H) {
    int o   = blockIdx.x + gridDim.x * blockIdx.y;   // 0..4351
    int xcd = o & 7;
    int j   = o >> 3;
    int mbi = xcd * MBPX + (j % MBPX);
    int nbi = j / MBPX;                              // 0..31
    int e = mb_e[mbi];
    if (e < 0) return;
    int m0 = mb_m0[mbi];
    int n0 = nbi * 128;
    const unsigned short* Bw = W1t + (size_t)e * F_ * D_;

    __shared__ __align__(16) unsigned short lA[2*BUFS];   // 32 KB (dbuf)
    __shared__ __align__(16) unsigned short lB[2*BUFS];   // 32 KB (dbuf)

    int t = threadIdx.x;
    int lane = t & 63;
    int wv = t >> 6;
    int wrow = (wv >> 1) * 64, wcol = (wv & 1) * 64;
    int lr = lane & 15, q = lane >> 4;
    int xork = lr & 7;        // read-side swizzle key (row&7 == lr&7)

    int sr = t >> 3;          // staging row 0..31 per pass
    int sc = ((t & 7) ^ (sr & 7)) * 8;   // pre-swizzled source chunk (ushorts)
    const unsigned short* pa[4];
    const unsigned short* pb[4];
    #pragma unroll
    for (int i = 0; i < 4; ++i) {
        int tok = perm[m0 + sr + 32*i];
        pa[i] = Xb + (size_t)tok * D_ + sc;
        pb[i] = Bw + (size_t)(n0 + sr + 32*i) * D_ + sc;
    }

    f32x4 acc[4][4];
    #pragma unroll
    for (int mi = 0; mi < 4; ++mi)
        #pragma unroll
        for (int ni = 0; ni < 4; ++ni)
            acc[mi][ni] = (f32x4){0.f, 0.f, 0.f, 0.f};

    // prologue: stage tile 0 into buffer 0
    #pragma unroll
    for (int i = 0; i < 4; ++i) {
        gl_lds16(pa[i], &lA[i*2048 + t*8]);
        gl_lds16(pb[i], &lB[i*2048 + t*8]);
    }

    const int KT = D_/BK;
    for (int kk = 0; kk < KT; ++kk) {
        int cur = (kk & 1) * BUFS;
        if (kk + 1 < KT) {
            int nxt = ((kk+1) & 1) * BUFS;
            int k0 = (kk+1) * BK;
            #pragma unroll
            for (int i = 0; i < 4; ++i) {
                gl_lds16(pa[i] + k0, &lA[nxt + i*2048 + t*8]);
                gl_lds16(pb[i] + k0, &lB[nxt + i*2048 + t*8]);
            }
            asm volatile("s_waitcnt vmcnt(8)" ::: "memory");
        } else {
            asm volatile("s_waitcnt vmcnt(0)" ::: "memory");
        }
        __builtin_amdgcn_s_barrier();     // all waves' tile-kk loads visible
        __builtin_amdgcn_sched_barrier(0);
        #pragma unroll
        for (int s = 0; s < 2; ++s) {
            short8 af[4], bf[4];
            #pragma unroll
            for (int mi = 0; mi < 4; ++mi)
                af[mi] = *(const short8*)&lA[cur + (wrow + mi*16 + lr)*BK + (((s*4+q) ^ xork) * 8)];
            #pragma unroll
            for (int ni = 0; ni < 4; ++ni)
                bf[ni] = *(const short8*)&lB[cur + (wcol + ni*16 + lr)*BK + (((s*4+q) ^ xork) * 8)];
            #pragma unroll
            for (int mi = 0; mi < 4; ++mi)
                #pragma unroll
                for (int ni = 0; ni < 4; ++ni)
                    acc[mi][ni] = __builtin_amdgcn_mfma_f32_16x16x32_bf16(
                        af[mi], bf[ni], acc[mi][ni], 0, 0, 0);
        }
        __builtin_amdgcn_sched_barrier(0);
        __builtin_amdgcn_s_barrier();     // reads of cur done; kk+2 may overwrite
    }

    const float* b1e = b1 + (size_t)e * F_;
    #pragma unroll
    for (int mi = 0; mi < 4; ++mi) {
        int gr = m0 + wrow + mi*16 + q*4;
        #pragma unroll
        for (int ni = 0; ni < 4; ++ni) {
            int f = n0 + wcol + ni*16 + lr;
            float bb = b1e[f];
            #pragma unroll
            for (int r = 0; r < 4; ++r) {
                float h = gelu_exact(acc[mi][ni][r] + bb);
                H[(size_t)(gr + r) * F_ + f] = f2b(h);
            }
        }
    }
}

// ---------------- GEMM2: Y[p] = H[p] @ W2[e] + b2[e] (bf16 stores) ---------
// same structure; K=4096 -> 64 iters, better prologue/epilogue amortization
__global__ __launch_bounds__(256, 2) void ffn2_kernel(
    const unsigned short* __restrict__ H, const unsigned short* __restrict__ W2t,
    const float* __restrict__ b2,
    const int* __restrict__ mb_e, const int* __restrict__ mb_m0,
    unsigned short* __restrict__ Y) {
    int o   = blockIdx.x + gridDim.x * blockIdx.y;   // 0..1087
    int xcd = o & 7;
    int j   = o >> 3;
    int mbi = xcd * MBPX + (j % MBPX);
    int nbi = j / MBPX;                              // 0..7
    int e = mb_e[mbi];
    if (e < 0) return;
    int m0 = mb_m0[mbi];
    int n0 = nbi * 128;
    const unsigned short* Bw = W2t + (size_t)e * D_ * F_;

    __shared__ __align__(16) unsigned short lA[2*BUFS];   // 32 KB
    __shared__ __align__(16) unsigned short lB[2*BUFS];   // 32 KB

    int t = threadIdx.x;
    int lane = t & 63;
    int wv = t >> 6;
    int wrow = (wv >> 1) * 64, wcol = (wv & 1) * 64;
    int lr = lane & 15, q = lane >> 4;
    int xork = lr & 7;

    int sr = t >> 3;
    int sc = ((t & 7) ^ (sr & 7)) * 8;   // pre-swizzled source chunk
    const unsigned short* pa[4];
    const unsigned short* pb[4];
    #pragma unroll
    for (int i = 0; i < 4; ++i) {
        pa[i] = H  + (size_t)(m0 + sr + 32*i) * F_ + sc;
        pb[i] = Bw + (size_t)(n0 + sr + 32*i) * F_ + sc;
    }

    f32x4 acc[4][4];
    #pragma unroll
    for (int mi = 0; mi < 4; ++mi)
        #pragma unroll
        for (int ni = 0; ni < 4; ++ni)
            acc[mi][ni] = (f32x4){0.f, 0.f, 0.f, 0.f};

    #pragma unroll
    for (int i = 0; i < 4; ++i) {
        gl_lds16(pa[i], &lA[i*2048 + t*8]);
        gl_lds16(pb[i], &lB[i*2048 + t*8]);
    }

    const int KT = F_/BK;
    for (int kk = 0; kk < KT; ++kk) {
        int cur = (kk & 1) * BUFS;
        if (kk + 1 < KT) {
            int nxt = ((kk+1) & 1) * BUFS;
            int k0 = (kk+1) * BK;
            #pragma unroll
            for (int i = 0; i < 4; ++i) {
                gl_lds16(pa[i] + k0, &lA[nxt + i*2048 + t*8]);
                gl_lds16(pb[i] + k0, &lB[nxt + i*2048 + t*8]);
            }
            asm volatile("s_waitcnt vmcnt(8)" ::: "memory");
        } else {
            asm volatile("s_waitcnt vmcnt(0)" ::: "memory");
        }
        __builtin_amdgcn_s_barrier();
        __builtin_amdgcn_sched_barrier(0);
        #pragma unroll
        for (int s = 0; s < 2; ++s) {
            short8 af[4], bf[4];
            #pragma unroll
            for (int mi = 0; mi < 4; ++mi)
                af[mi] = *(const short8*)&lA[cur + (wrow + mi*16 + lr)*BK + (((s*4+q) ^ xork) * 8)];
            #pragma unroll
            for (int ni = 0; ni < 4; ++ni)
                bf[ni] = *(const short8*)&lB[cur + (wcol + ni*16 + lr)*BK + (((s*4+q) ^ xork) * 8)];
            #pragma unroll
            for (int mi = 0; mi < 4; ++mi)
                #pragma unroll
                for (int ni = 0; ni < 4; ++ni)
                    acc[mi][ni] = __builtin_amdgcn_mfma_f32_16x16x32_bf16(
                        af[mi], bf[ni], acc[mi][ni], 0, 0, 0);
        }
        __builtin_amdgcn_sched_barrier(0);
        __builtin_amdgcn_s_barrier();
    }

    const float* b2e = b2 + (size_t)e * D_;
    #pragma unroll
    for (int mi = 0; mi < 4; ++mi) {
        int gr = m0 + wrow + mi*16 + q*4;
        #pragma unroll
        for (int ni = 0; ni < 4; ++ni) {
            int dcol = n0 + wcol + ni*16 + lr;
            float bb = b2e[dcol];
            #pragma unroll
            for (int r = 0; r < 4; ++r)
                Y[(size_t)(gr + r) * D_ + dcol] = f2b(acc[mi][ni][r] + bb);
        }
    }
}

// ---------------- combine: out[t] = w0*Y[s0] + w1*Y[s1] ----------------
__global__ __launch_bounds__(256) void combine_kernel(
    const unsigned short* __restrict__ Y, const int* __restrict__ slots,
    const float* __restrict__ topw, float* __restrict__ out) {
    int t  = blockIdx.x;
    int d4 = threadIdx.x * 4;
    int s0 = slots[t*2], s1 = slots[t*2+1];
    float w0 = topw[t*2], w1 = topw[t*2+1];
    ushort4 y0 = *(const ushort4*)&Y[(size_t)s0 * D_ + d4];
    ushort4 y1 = *(const ushort4*)&Y[(size_t)s1 * D_ + d4];
    float4 o;
    o.x = w0*b2f(y0.x) + w1*b2f(y1.x);
    o.y = w0*b2f(y0.y) + w1*b2f(y1.y);
    o.z = w0*b2f(y0.z) + w1*b2f(y1.z);
    o.w = w0*b2f(y0.w) + w1*b2f(y1.w);
    *(float4*)&out[(size_t)t * D_ + d4] = o;
}

extern "C" void kernel_launch(void* const* d_in, const int* in_sizes, int n_in,
                              void* d_out, int out_size, void* d_ws, size_t ws_size,
                              hipStream_t stream) {
    const float* x  = (const float*)d_in[0];
    const float* Wg = (const float*)d_in[1];
    const float* bg = (const float*)d_in[2];
    const float* W1 = (const float*)d_in[3];
    const float* b1 = (const float*)d_in[4];
    const float* W2 = (const float*)d_in[5];
    const float* b2 = (const float*)d_in[6];
    float* out = (float*)d_out;

    char* wsp = (char*)d_ws;
    size_t off = 0;
    auto alloc = [&](size_t bytes) {
        void* p = wsp + off;
        off += (bytes + 255) & ~(size_t)255;
        return p;
    };
    int*   topi    = (int*)  alloc((size_t)NR_*4);
    float* topw    = (float*)alloc((size_t)NR_*4);
    int*   slots   = (int*)  alloc((size_t)NR_*4);
    int*   counts  = (int*)  alloc(E_*4);
    int*   offs    = (int*)  alloc((E_+1)*4);
    int*   cursors = (int*)  alloc(E_*4);
    int*   mb_e    = (int*)  alloc(MAXMB*4);
    int*   mb_m0   = (int*)  alloc(MAXMB*4);
    int*   perm    = (int*)  alloc((size_t)MAXP*4);
    unsigned short* Xb  = (unsigned short*)alloc((size_t)N_*D_*2);
    unsigned short* W1t = (unsigned short*)alloc((size_t)E_*D_*F_*2);
    unsigned short* W2t = (unsigned short*)alloc((size_t)E_*D_*F_*2);
    unsigned short* Hb  = (unsigned short*)alloc((size_t)MAXP*F_*2);
    unsigned short* Yb  = (unsigned short*)alloc((size_t)MAXP*D_*2);

    hipMemsetAsync(counts, 0, E_*4, stream);
    hipMemsetAsync(perm, 0, (size_t)MAXP*4, stream);

    gate_kernel<<<N_/4, 256, 0, stream>>>(x, Wg, bg, topi, topw, counts, Xb);
    scan_kernel<<<1, 64, 0, stream>>>(counts, offs, cursors, mb_e, mb_m0);
    scatter_kernel<<<N_/256, 256, 0, stream>>>(topi, cursors, perm, slots);
    tcast_kernel<<<dim3(D_/64, F_/64, E_), 256, 0, stream>>>(W1, W1t, D_, F_);
    tcast_kernel<<<dim3(F_/64, D_/64, E_), 256, 0, stream>>>(W2, W2t, F_, D_);
    ffn1_kernel<<<dim3(MAXMB, F_/128), 256, 0, stream>>>(Xb, W1t, b1, perm, mb_e, mb_m0, Hb);
    ffn2_kernel<<<dim3(MAXMB, D_/128), 256, 0, stream>>>(Hb, W2t, b2, mb_e, mb_m0, Yb);
    combine_kernel<<<N_, 256, 0, stream>>>(Yb, slots, topw, out);
}

// Round 6
// 1043.405 us; speedup vs baseline: 1.0552x; 1.0552x over previous
//
#include <hip/hip_runtime.h>
#include <cstdint>

#define B_ 4
#define T_ 2048
#define D_ 1024
#define E_ 8
#define F_ 4096
#define K_ 2
#define N_ (B_*T_)      // 8192 tokens
#define NR_ (N_*K_)     // 16384 routed slots

#define TM1 256                  // ffn1 M-block (8-phase 256^2)
#define TM2 128                  // ffn2 M-block (2-phase 128^2)
#define BK 64
#define MAXP (NR_ + E_*TM1)      // padded slot capacity (18432), 256-aligned segs
#define MB1 (NR_/TM1 + E_)       // 72 == 8 XCDs * 9
#define MB2 (NR_/TM2 + E_)       // 136 == 8 XCDs * 17
#define MBPX1 (MB1/8)            // 9
#define MBPX2 (MB2/8)            // 17

typedef __attribute__((ext_vector_type(8))) short short8;
typedef __attribute__((ext_vector_type(4))) float f32x4;

typedef const __attribute__((address_space(1))) unsigned int* gp1_t;
typedef __attribute__((address_space(3))) unsigned int* lp3_t;

__device__ __forceinline__ void gl_lds16(const void* g, void* l) {
    __builtin_amdgcn_global_load_lds((gp1_t)g, (lp3_t)l, 16, 0, 0);
}

__device__ __forceinline__ unsigned short f2b(float f) {
    union { float f; unsigned int u; } v; v.f = f;
    unsigned int u = v.u;
    return (unsigned short)((u + 0x7FFFu + ((u >> 16) & 1u)) >> 16);
}

__device__ __forceinline__ float b2f(unsigned short u) {
    union { unsigned int i; float f; } v; v.i = ((unsigned int)u) << 16;
    return v.f;
}

__device__ __forceinline__ float gelu_exact(float x) {
    return 0.5f * x * (1.0f + erff(x * 0.70710678118654752440f));
}

// ---------------- gate: fp32 logits, top-2, softmax; fused x->bf16 cast ----
__global__ __launch_bounds__(256) void gate_kernel(
    const float* __restrict__ x, const float* __restrict__ Wg,
    const float* __restrict__ bg, int* __restrict__ topi,
    float* __restrict__ topw, int* __restrict__ counts,
    unsigned short* __restrict__ Xb) {
    int tid  = threadIdx.x;
    int lane = tid & 63;
    int tok  = blockIdx.x * 4 + (tid >> 6);
    int e = lane & 7;
    int c = lane >> 3;
    const float4* xp = (const float4*)(x + (size_t)tok * D_ + c * 128);
    const float*  wp = Wg + (size_t)(c * 128) * E_ + e;
    float acc = 0.f;
    #pragma unroll 8
    for (int i = 0; i < 32; ++i) {
        float4 xv = xp[i];
        acc += xv.x * wp[(i*4+0)*E_];
        acc += xv.y * wp[(i*4+1)*E_];
        acc += xv.z * wp[(i*4+2)*E_];
        acc += xv.w * wp[(i*4+3)*E_];
    }
    // fused bf16 cast: lane owns floats [lane*16, lane*16+16) (L1-hot re-read)
    {
        const float4* xw = (const float4*)(x + (size_t)tok * D_ + lane * 16);
        #pragma unroll
        for (int j = 0; j < 4; ++j) {
            float4 v = xw[j];
            ushort4 o; o.x = f2b(v.x); o.y = f2b(v.y); o.z = f2b(v.z); o.w = f2b(v.w);
            *(ushort4*)&Xb[(size_t)tok * D_ + lane*16 + j*4] = o;
        }
    }
    acc += __shfl_xor(acc, 8, 64);
    acc += __shfl_xor(acc, 16, 64);
    acc += __shfl_xor(acc, 32, 64);
    float logit = acc + bg[e];
    float v1 = -3.4e38f, v2 = -3.4e38f; int i1 = -1, i2 = -1;
    for (int ee = 0; ee < 8; ++ee) {
        float le = __shfl(logit, ee, 64);
        if (le > v1) { v2 = v1; i2 = i1; v1 = le; i1 = ee; }
        else if (le > v2) { v2 = le; i2 = ee; }
    }
    if (lane == 0) {
        float p2 = expf(v2 - v1);
        float s  = 1.0f + p2;
        topi[tok*2]   = i1; topw[tok*2]   = 1.0f / s;
        topi[tok*2+1] = i2; topw[tok*2+1] = p2 / s;
        atomicAdd(&counts[i1], 1);
        atomicAdd(&counts[i2], 1);
    }
}

// scan: 256-aligned per-expert segments; dual M-block tables (256 and 128)
__global__ void scan_kernel(const int* __restrict__ counts,
                            int* __restrict__ offs, int* __restrict__ cursors,
                            int* __restrict__ mb1_e, int* __restrict__ mb1_m0,
                            int* __restrict__ mb2_e, int* __restrict__ mb2_m0) {
    if (threadIdx.x == 0) {
        int s = 0, a = 0, b = 0;
        for (int e = 0; e < E_; ++e) {
            offs[e] = s; cursors[e] = s;
            int c = counts[e];
            int nb1 = (c + TM1 - 1) / TM1;
            for (int i = 0; i < nb1; ++i) { mb1_e[a] = e; mb1_m0[a] = s + i*TM1; ++a; }
            int nb2 = (c + TM2 - 1) / TM2;
            for (int i = 0; i < nb2; ++i) { mb2_e[b] = e; mb2_m0[b] = s + i*TM2; ++b; }
            s += nb1 * TM1;
        }
        offs[E_] = s;
        for (; a < MB1; ++a) mb1_e[a] = -1;
        for (; b < MB2; ++b) mb2_e[b] = -1;
    }
}

// wave-aggregated scatter
__global__ __launch_bounds__(256) void scatter_kernel(
    const int* __restrict__ topi, int* __restrict__ cursors,
    int* __restrict__ perm, int* __restrict__ slots) {
    int t = blockIdx.x * blockDim.x + threadIdx.x;
    int lane = threadIdx.x & 63;
    unsigned long long lanebit_m1 = (1ULL << lane) - 1ULL;
    #pragma unroll
    for (int k = 0; k < K_; ++k) {
        int e = (t < N_) ? topi[t*2 + k] : -1;
        int pos = 0;
        #pragma unroll
        for (int ee = 0; ee < E_; ++ee) {
            unsigned long long mask = __ballot(e == ee);
            if (mask) {
                int leader = __ffsll((long long)mask) - 1;
                int base = 0;
                if (lane == leader)
                    base = atomicAdd(&cursors[ee], __popcll(mask));
                base = __shfl(base, leader, 64);
                if (e == ee)
                    pos = base + __popcll(mask & lanebit_m1);
            }
        }
        if (t < N_) {
            perm[pos] = t;
            slots[t*2 + k] = pos;
        }
    }
}

// batched fp32 [R,C] -> bf16 [C,R]; 64x64 tile, vectorized
__global__ __launch_bounds__(256) void tcast_kernel(
    const float* __restrict__ src, unsigned short* __restrict__ dst, int R, int C) {
    __shared__ float tile[64][65];
    int rb = blockIdx.x * 64, cb = blockIdx.y * 64;
    const float* s = src + (size_t)blockIdx.z * R * C;
    unsigned short* d = dst + (size_t)blockIdx.z * R * C;
    int tx = threadIdx.x & 15, ty = threadIdx.x >> 4;
    #pragma unroll
    for (int i = 0; i < 4; ++i) {
        int r = ty + i*16;
        float4 v = *(const float4*)&s[(size_t)(rb + r) * C + cb + tx*4];
        tile[r][tx*4+0] = v.x; tile[r][tx*4+1] = v.y;
        tile[r][tx*4+2] = v.z; tile[r][tx*4+3] = v.w;
    }
    __syncthreads();
    #pragma unroll
    for (int i = 0; i < 4; ++i) {
        int c = ty + i*16;
        ushort4 o;
        o.x = f2b(tile[tx*4+0][c]);
        o.y = f2b(tile[tx*4+1][c]);
        o.z = f2b(tile[tx*4+2][c]);
        o.w = f2b(tile[tx*4+3][c]);
        *(ushort4*)&d[(size_t)(cb + c) * R + rb + tx*4] = o;
    }
}

// ---------------- GEMM1: 256x256 8-phase (T2+T3+T4+T5) ----------------
// 512 thr / 8 waves (2M x 4N), per-wave out 128x64, LDS 128 KB, 1 blk/CU.
// Stage order per K-tile {B0,B1,A0,A1}; during tile t's phases stage
// {t+1.A1, t+2.B0, t+2.B1, t+2.A0}. Reads: P0 = A-lo(8) + B-all(8),
// P1 = A-hi(8); lgkmcnt(0) drains each phase's reads before its end, so
// every region is fully read before its overwrite can land. vmcnt(6) at P3
// retires exactly tile t+1 (ledger: 6 newest = t+2's B0,B1,A0).
__global__ __launch_bounds__(512, 2) void ffn1_kernel(
    const unsigned short* __restrict__ Xb, const unsigned short* __restrict__ W1t,
    const float* __restrict__ b1, const int* __restrict__ perm,
    const int* __restrict__ mb1_e, const int* __restrict__ mb1_m0,
    unsigned short* __restrict__ H) {
    int o   = blockIdx.x + gridDim.x * blockIdx.y;   // 0..1151
    int xcd = o & 7;
    int jj  = o >> 3;                                // 0..143
    int mbi = xcd * MBPX1 + jj % MBPX1;
    int nbi = jj / MBPX1;                            // 0..15
    int e = mb1_e[mbi];
    if (e < 0) return;
    int m0 = mb1_m0[mbi];
    int n0 = nbi * 256;
    const unsigned short* Bw = W1t + (size_t)e * F_ * D_;

    __shared__ __align__(16) unsigned short lA[32768];   // [slot][half][128][64]
    __shared__ __align__(16) unsigned short lB[32768];

    int t = threadIdx.x, lane = t & 63, wid = t >> 6;
    int wm = wid >> 2, wn = wid & 3;                 // 2M x 4N
    int lr = lane & 15, q = lane >> 4, xork = lr & 7;
    int bh = wn >> 1, bro = (wn & 1) * 64;           // B half + row base

    int srow = t >> 3;                               // 0..63
    int swch = ((t & 7) ^ (srow & 7)) * 8;           // inverse-swizzled src chunk
    const unsigned short* pA[2][2];
    const unsigned short* pB[2][2];
    #pragma unroll
    for (int h = 0; h < 2; ++h)
        #pragma unroll
        for (int l = 0; l < 2; ++l) {
            int r = srow + l * 64;
            pA[h][l] = Xb + (size_t)perm[m0 + h*128 + r] * D_ + swch;
            pB[h][l] = Bw + (size_t)(n0 + h*128 + r) * D_ + swch;
        }

    f32x4 acc[8][4];
    #pragma unroll
    for (int m = 0; m < 8; ++m)
        #pragma unroll
        for (int n = 0; n < 4; ++n)
            acc[m][n] = (f32x4){0.f, 0.f, 0.f, 0.f};

#define STG_B(tile, h) do { int _s = ((tile)&1)*16384 + (h)*8192; int _k = (tile)*BK; \
        gl_lds16(pB[h][0] + _k, &lB[_s + t*8]); \
        gl_lds16(pB[h][1] + _k, &lB[_s + 4096 + t*8]); } while (0)
#define STG_A(tile, h) do { int _s = ((tile)&1)*16384 + (h)*8192; int _k = (tile)*BK; \
        gl_lds16(pA[h][0] + _k, &lA[_s + t*8]); \
        gl_lds16(pA[h][1] + _k, &lA[_s + 4096 + t*8]); } while (0)

    // prologue: tile0 full (4 ht), pace, tile1 B0,B1,A0 (3 ht)
    STG_B(0, 0); STG_B(0, 1); STG_A(0, 0); STG_A(0, 1);
    asm volatile("s_waitcnt vmcnt(4)" ::: "memory");
    STG_B(1, 0); STG_B(1, 1); STG_A(1, 0);
    asm volatile("s_waitcnt vmcnt(6)" ::: "memory");   // tile0 resident
    __builtin_amdgcn_s_barrier();

    const int KT = D_ / BK;                          // 16
    for (int tt = 0; tt < KT; ++tt) {
        int cur = (tt & 1) * 16384;
        short8 af[8][2], bf[4][2];
        // ---- P0: read A m0-3 + B all; stage (t+1).A1; MFMA m0-3 x n0-1
        #pragma unroll
        for (int m = 0; m < 4; ++m)
            #pragma unroll
            for (int s = 0; s < 2; ++s)
                af[m][s] = *(const short8*)&lA[cur + wm*8192 + (m*16+lr)*64 + (((s*4+q)^xork)*8)];
        #pragma unroll
        for (int n = 0; n < 4; ++n)
            #pragma unroll
            for (int s = 0; s < 2; ++s)
                bf[n][s] = *(const short8*)&lB[cur + bh*8192 + (bro + n*16 + lr)*64 + (((s*4+q)^xork)*8)];
        if (tt + 1 < KT) STG_A(tt + 1, 1);
        __builtin_amdgcn_sched_barrier(0);
        __builtin_amdgcn_s_barrier();
        asm volatile("s_waitcnt lgkmcnt(0)" ::: "memory");
        __builtin_amdgcn_sched_barrier(0);
        __builtin_amdgcn_s_setprio(1);
        #pragma unroll
        for (int m = 0; m < 4; ++m)
            #pragma unroll
            for (int n = 0; n < 2; ++n)
                #pragma unroll
                for (int s = 0; s < 2; ++s)
                    acc[m][n] = __builtin_amdgcn_mfma_f32_16x16x32_bf16(af[m][s], bf[n][s], acc[m][n], 0, 0, 0);
        __builtin_amdgcn_s_setprio(0);
        __builtin_amdgcn_sched_barrier(0);
        __builtin_amdgcn_s_barrier();
        // ---- P1: read A m4-7; stage (t+2).B0; MFMA m0-3 x n2-3
        #pragma unroll
        for (int m = 4; m < 8; ++m)
            #pragma unroll
            for (int s = 0; s < 2; ++s)
                af[m][s] = *(const short8*)&lA[cur + wm*8192 + (m*16+lr)*64 + (((s*4+q)^xork)*8)];
        if (tt + 2 < KT) STG_B(tt + 2, 0);
        __builtin_amdgcn_sched_barrier(0);
        __builtin_amdgcn_s_barrier();
        asm volatile("s_waitcnt lgkmcnt(0)" ::: "memory");
        __builtin_amdgcn_sched_barrier(0);
        __builtin_amdgcn_s_setprio(1);
        #pragma unroll
        for (int m = 0; m < 4; ++m)
            #pragma unroll
            for (int n = 2; n < 4; ++n)
                #pragma unroll
                for (int s = 0; s < 2; ++s)
                    acc[m][n] = __builtin_amdgcn_mfma_f32_16x16x32_bf16(af[m][s], bf[n][s], acc[m][n], 0, 0, 0);
        __builtin_amdgcn_s_setprio(0);
        __builtin_amdgcn_sched_barrier(0);
        __builtin_amdgcn_s_barrier();
        // ---- P2: stage (t+2).B1; MFMA m4-7 x n0-1
        if (tt + 2 < KT) STG_B(tt + 2, 1);
        __builtin_amdgcn_sched_barrier(0);
        __builtin_amdgcn_s_barrier();
        __builtin_amdgcn_sched_barrier(0);
        __builtin_amdgcn_s_setprio(1);
        #pragma unroll
        for (int m = 4; m < 8; ++m)
            #pragma unroll
            for (int n = 0; n < 2; ++n)
                #pragma unroll
                for (int s = 0; s < 2; ++s)
                    acc[m][n] = __builtin_amdgcn_mfma_f32_16x16x32_bf16(af[m][s], bf[n][s], acc[m][n], 0, 0, 0);
        __builtin_amdgcn_s_setprio(0);
        __builtin_amdgcn_sched_barrier(0);
        __builtin_amdgcn_s_barrier();
        // ---- P3: stage (t+2).A0; MFMA m4-7 x n2-3; vmcnt; barrier
        if (tt + 2 < KT) STG_A(tt + 2, 0);
        __builtin_amdgcn_sched_barrier(0);
        __builtin_amdgcn_s_barrier();
        __builtin_amdgcn_sched_barrier(0);
        __builtin_amdgcn_s_setprio(1);
        #pragma unroll
        for (int m = 4; m < 8; ++m)
            #pragma unroll
            for (int n = 2; n < 4; ++n)
                #pragma unroll
                for (int s = 0; s < 2; ++s)
                    acc[m][n] = __builtin_amdgcn_mfma_f32_16x16x32_bf16(af[m][s], bf[n][s], acc[m][n], 0, 0, 0);
        __builtin_amdgcn_s_setprio(0);
        __builtin_amdgcn_sched_barrier(0);
        if (tt < KT - 2) { asm volatile("s_waitcnt vmcnt(6)" ::: "memory"); }
        else             { asm volatile("s_waitcnt vmcnt(0)" ::: "memory"); }
        __builtin_amdgcn_s_barrier();                // tile tt+1 resident
    }
#undef STG_A
#undef STG_B

    const float* b1e = b1 + (size_t)e * F_;
    #pragma unroll
    for (int m = 0; m < 8; ++m) {
        int gr = m0 + wm*128 + m*16 + q*4;
        #pragma unroll
        for (int n = 0; n < 4; ++n) {
            int fc = n0 + wn*64 + n*16 + lr;
            float bb = b1e[fc];
            #pragma unroll
            for (int r = 0; r < 4; ++r) {
                float h = gelu_exact(acc[m][n][r] + bb);
                H[(size_t)(gr + r) * F_ + fc] = f2b(h);
            }
        }
    }
}

// ---------------- GEMM2: proven r2 2-phase 128x128 (947-us config) --------
__global__ __launch_bounds__(256, 4) void ffn2_kernel(
    const unsigned short* __restrict__ H, const unsigned short* __restrict__ W2t,
    const float* __restrict__ b2,
    const int* __restrict__ mb2_e, const int* __restrict__ mb2_m0,
    unsigned short* __restrict__ Y) {
    int o   = blockIdx.x + gridDim.x * blockIdx.y;   // 0..1087
    int xcd = o & 7;
    int j   = o >> 3;
    int mbi = xcd * MBPX2 + (j % MBPX2);
    int nbi = j / MBPX2;                             // 0..7
    int e = mb2_e[mbi];
    if (e < 0) return;
    int m0 = mb2_m0[mbi];
    int n0 = nbi * 128;
    const unsigned short* Bw = W2t + (size_t)e * D_ * F_;

    __shared__ __align__(16) unsigned short lA[128*BK];   // 16 KB
    __shared__ __align__(16) unsigned short lB[128*BK];   // 16 KB

    int t = threadIdx.x;
    int lane = t & 63;
    int wv = t >> 6;
    int wrow = (wv >> 1) * 64, wcol = (wv & 1) * 64;
    int lr = lane & 15, q = lane >> 4;
    int xork = lr & 7;

    int sr = t >> 3;
    int sc = ((t & 7) ^ (sr & 7)) * 8;
    const unsigned short* pa[4];
    const unsigned short* pb[4];
    #pragma unroll
    for (int i = 0; i < 4; ++i) {
        pa[i] = H  + (size_t)(m0 + sr + 32*i) * F_ + sc;
        pb[i] = Bw + (size_t)(n0 + sr + 32*i) * F_ + sc;
    }

    f32x4 acc[4][4];
    #pragma unroll
    for (int mi = 0; mi < 4; ++mi)
        #pragma unroll
        for (int ni = 0; ni < 4; ++ni)
            acc[mi][ni] = (f32x4){0.f, 0.f, 0.f, 0.f};

    for (int kk = 0; kk < F_/BK; ++kk) {
        int k0 = kk * BK;
        #pragma unroll
        for (int i = 0; i < 4; ++i) {
            gl_lds16(pa[i] + k0, &lA[i*2048 + t*8]);
            gl_lds16(pb[i] + k0, &lB[i*2048 + t*8]);
        }
        asm volatile("s_waitcnt vmcnt(0)" ::: "memory");
        __syncthreads();
        #pragma unroll
        for (int s = 0; s < 2; ++s) {
            short8 af[4], bf[4];
            #pragma unroll
            for (int mi = 0; mi < 4; ++mi)
                af[mi] = *(const short8*)&lA[(wrow + mi*16 + lr)*BK + (((s*4+q) ^ xork) * 8)];
            #pragma unroll
            for (int ni = 0; ni < 4; ++ni)
                bf[ni] = *(const short8*)&lB[(wcol + ni*16 + lr)*BK + (((s*4+q) ^ xork) * 8)];
            #pragma unroll
            for (int mi = 0; mi < 4; ++mi)
                #pragma unroll
                for (int ni = 0; ni < 4; ++ni)
                    acc[mi][ni] = __builtin_amdgcn_mfma_f32_16x16x32_bf16(
                        af[mi], bf[ni], acc[mi][ni], 0, 0, 0);
        }
        __syncthreads();
    }

    const float* b2e = b2 + (size_t)e * D_;
    #pragma unroll
    for (int mi = 0; mi < 4; ++mi) {
        int gr = m0 + wrow + mi*16 + q*4;
        #pragma unroll
        for (int ni = 0; ni < 4; ++ni) {
            int dcol = n0 + wcol + ni*16 + lr;
            float bb = b2e[dcol];
            #pragma unroll
            for (int r = 0; r < 4; ++r)
                Y[(size_t)(gr + r) * D_ + dcol] = f2b(acc[mi][ni][r] + bb);
        }
    }
}

// ---------------- combine: out[t] = w0*Y[s0] + w1*Y[s1] ----------------
__global__ __launch_bounds__(256) void combine_kernel(
    const unsigned short* __restrict__ Y, const int* __restrict__ slots,
    const float* __restrict__ topw, float* __restrict__ out) {
    int t  = blockIdx.x;
    int d4 = threadIdx.x * 4;
    int s0 = slots[t*2], s1 = slots[t*2+1];
    float w0 = topw[t*2], w1 = topw[t*2+1];
    ushort4 y0 = *(const ushort4*)&Y[(size_t)s0 * D_ + d4];
    ushort4 y1 = *(const ushort4*)&Y[(size_t)s1 * D_ + d4];
    float4 o;
    o.x = w0*b2f(y0.x) + w1*b2f(y1.x);
    o.y = w0*b2f(y0.y) + w1*b2f(y1.y);
    o.z = w0*b2f(y0.z) + w1*b2f(y1.z);
    o.w = w0*b2f(y0.w) + w1*b2f(y1.w);
    *(float4*)&out[(size_t)t * D_ + d4] = o;
}

extern "C" void kernel_launch(void* const* d_in, const int* in_sizes, int n_in,
                              void* d_out, int out_size, void* d_ws, size_t ws_size,
                              hipStream_t stream) {
    const float* x  = (const float*)d_in[0];
    const float* Wg = (const float*)d_in[1];
    const float* bg = (const float*)d_in[2];
    const float* W1 = (const float*)d_in[3];
    const float* b1 = (const float*)d_in[4];
    const float* W2 = (const float*)d_in[5];
    const float* b2 = (const float*)d_in[6];
    float* out = (float*)d_out;

    char* wsp = (char*)d_ws;
    size_t off = 0;
    auto alloc = [&](size_t bytes) {
        void* p = wsp + off;
        off += (bytes + 255) & ~(size_t)255;
        return p;
    };
    int*   topi    = (int*)  alloc((size_t)NR_*4);
    float* topw    = (float*)alloc((size_t)NR_*4);
    int*   slots   = (int*)  alloc((size_t)NR_*4);
    int*   counts  = (int*)  alloc(E_*4);
    int*   offs    = (int*)  alloc((E_+1)*4);
    int*   cursors = (int*)  alloc(E_*4);
    int*   mb1_e   = (int*)  alloc(MB1*4);
    int*   mb1_m0  = (int*)  alloc(MB1*4);
    int*   mb2_e   = (int*)  alloc(MB2*4);
    int*   mb2_m0  = (int*)  alloc(MB2*4);
    int*   perm    = (int*)  alloc((size_t)MAXP*4);
    unsigned short* Xb  = (unsigned short*)alloc((size_t)N_*D_*2);
    unsigned short* W1t = (unsigned short*)alloc((size_t)E_*D_*F_*2);
    unsigned short* W2t = (unsigned short*)alloc((size_t)E_*D_*F_*2);
    unsigned short* Hb  = (unsigned short*)alloc((size_t)MAXP*F_*2);
    unsigned short* Yb  = (unsigned short*)alloc((size_t)MAXP*D_*2);

    hipMemsetAsync(counts, 0, E_*4, stream);
    hipMemsetAsync(perm, 0, (size_t)MAXP*4, stream);

    gate_kernel<<<N_/4, 256, 0, stream>>>(x, Wg, bg, topi, topw, counts, Xb);
    scan_kernel<<<1, 64, 0, stream>>>(counts, offs, cursors, mb1_e, mb1_m0, mb2_e, mb2_m0);
    scatter_kernel<<<N_/256, 256, 0, stream>>>(topi, cursors, perm, slots);
    tcast_kernel<<<dim3(D_/64, F_/64, E_), 256, 0, stream>>>(W1, W1t, D_, F_);
    tcast_kernel<<<dim3(F_/64, D_/64, E_), 256, 0, stream>>>(W2, W2t, F_, D_);
    ffn1_kernel<<<dim3(MB1, F_/256), 512, 0, stream>>>(Xb, W1t, b1, perm, mb1_e, mb1_m0, Hb);
    ffn2_kernel<<<dim3(MB2, D_/128), 256, 0, stream>>>(Hb, W2t, b2, mb2_e, mb2_m0, Yb);
    combine_kernel<<<N_, 256, 0, stream>>>(Yb, slots, topw, out);
}